// Round 12
// baseline (409.006 us; speedup 1.0000x reference)
//
#include <hip/hip_runtime.h>
#include <hip/hip_bf16.h>

// ChebConv K=4. out[b,v,o] = bias[o] + sum_{c<256} xs[c&3][v,(c>>2)*2+b] * Wflat[c*64+o]
// R12: feature-sliced spmm — x stored as 4 slabs of 3.2MB (x[arr][slice][v][32 u16]);
// wave = (row, slice), 64B/edge gathers from an L2-resident slab; slices phased by
// blockIdx. 16 edges per dwordx4 instruction, butterfly reduce. CSR build = R11.

#define NV 50000
#define NE 800000
#define NROWS 100000
#define NTILES 6250    // NROWS / 16
#define SCAN_NBLK 196
#define EPMAX 1600000  // >= NE + 15*NV (padded CSR upper bound)
#define SLAB 800000    // NV*16 uints per slice slab (3.2 MB)

using u16 = unsigned short;
using u32 = unsigned int;
typedef __bf16 bf16x8 __attribute__((ext_vector_type(8)));
typedef float f32x4 __attribute__((ext_vector_type(4)));

__device__ __forceinline__ float bflo(u32 g) { return __uint_as_float(g << 16); }
__device__ __forceinline__ float bfhi(u32 g) { return __uint_as_float(g & 0xffff0000u); }
__device__ __forceinline__ u32 pack_bf2(float a, float b) {
    u16 ha = __builtin_bit_cast(u16, (__bf16)a);
    u16 hb = __builtin_bit_cast(u16, (__bf16)b);
    return (u32)ha | ((u32)hb << 16);
}
__device__ __forceinline__ float unpack_f16hi(u32 rec) {
    u16 h = (u16)(rec >> 16);
    return (float)__builtin_bit_cast(_Float16, h);
}
__device__ __forceinline__ int pad16(int n) { return (n + 15) & ~15; }

__global__ void hist_k(const int* __restrict__ rows, int* __restrict__ cnt) {
    int i = blockIdx.x * blockDim.x + threadIdx.x;
    if (i < NE) atomicAdd(&cnt[rows[i]], 1);
}

__global__ __launch_bounds__(256) void scan1_k(const int* __restrict__ cnt, int* __restrict__ bsum) {
    __shared__ int s[256];
    int t = threadIdx.x;
    int i = blockIdx.x * 256 + t;
    s[t] = (i < NV) ? pad16(cnt[i]) : 0;
    __syncthreads();
    for (int off = 128; off > 0; off >>= 1) {
        if (t < off) s[t] += s[t + off];
        __syncthreads();
    }
    if (t == 0) bsum[blockIdx.x] = s[0];
}

__global__ __launch_bounds__(256) void scan2_k(int* __restrict__ bsum) {
    __shared__ int s[256];
    int t = threadIdx.x;
    s[t] = (t < SCAN_NBLK) ? bsum[t] : 0;
    __syncthreads();
    for (int off = 1; off < 256; off <<= 1) {
        int v = (t >= off) ? s[t - off] : 0;
        __syncthreads();
        s[t] += v;
        __syncthreads();
    }
    if (t < SCAN_NBLK) bsum[t] = (t == 0) ? 0 : s[t - 1];
}

__global__ __launch_bounds__(256) void scan3_k(const int* __restrict__ cnt, const int* __restrict__ bsum,
                                               int* __restrict__ row_ptr, int* __restrict__ row_fill) {
    __shared__ int s[256];
    int t = threadIdx.x;
    int i = blockIdx.x * 256 + t;
    int myv = (i < NV) ? pad16(cnt[i]) : 0;
    s[t] = myv;
    __syncthreads();
    for (int off = 1; off < 256; off <<= 1) {
        int v = (t >= off) ? s[t - off] : 0;
        __syncthreads();
        s[t] += v;
        __syncthreads();
    }
    if (i < NV) {
        int p = bsum[blockIdx.x] + s[t] - myv;
        row_ptr[i] = p;
        row_fill[i] = p;
        if (i == NV - 1) row_ptr[NV] = p + myv;
    }
}

// One 4B store per edge: rec = col | f16(val)<<16. Pad slots stay 0 from memset.
__global__ void scatter_k(const int* __restrict__ rows, const int* __restrict__ cols,
                          const float* __restrict__ vals,
                          int* __restrict__ row_fill,
                          u32* __restrict__ epack) {
    int i = blockIdx.x * blockDim.x + threadIdx.x;
    if (i < NE) {
        int r = rows[i];
        int p = atomicAdd(&row_fill[r], 1);
        u16 hv = __builtin_bit_cast(u16, (_Float16)vals[i]);
        epack[p] = (u32)cols[i] | ((u32)hv << 16);
    }
}

// x0 slabs: uint dst = slice*SLAB + v*16 + (p&15), slice = p>>4, where p is the
// uint index within the row layout [b*64+f] (uint p covers u16 2p, 2p+1).
__global__ void build_x0_k(const float* __restrict__ in, u32* __restrict__ x0u) {
    int i = blockIdx.x * blockDim.x + threadIdx.x;  // v*64 + p
    if (i < NV * 64) {
        int v = i >> 6, p = i & 63;
        int b = p >> 5;
        int f = (p & 31) * 2;
        const float* src = in + (size_t)b * (NV * 64) + (size_t)v * 64 + f;
        float2 t = *(const float2*)src;
        x0u[(size_t)(p >> 4) * SLAB + (size_t)v * 16 + (p & 15)] = pack_bf2(t.x, t.y);
    }
}

// Pre-permute weight to bf16 image: wimg[o*264 + c'] = bf16(Wflat[c*64+o]).
__global__ void prep_w_k(const float* __restrict__ weight, u16* __restrict__ wimg) {
    int i = blockIdx.x * blockDim.x + threadIdx.x;
    if (i < 256 * 64) {
        int c = i >> 6, o = i & 63;
        int cp = ((c & 3) << 6) | (c >> 2);
        wimg[o * 264 + cp] = __builtin_bit_cast(u16, (__bf16)weight[i]);
    }
}

// Sliced pull spmm. Wave = (row, slice); slice = blockIdx/12500 (temporal phasing).
// Lane: es = lane>>2 (16 edges/iter), c4 = lane&3 (16B chunk of the 64B slice row).
// One dwordx4 gather serves 16 edges. Butterfly xor 4,8,16,32; lanes 0-3 store.
// mode 0: L x ; 1: 2 L x - xprev. Rows padded to 16-edge multiples (tail-free).
__global__ __launch_bounds__(256) void spmm_k(const u32* __restrict__ x,
                                              const u32* __restrict__ xprev,
                                              const int* __restrict__ row_ptr,
                                              const u32* __restrict__ epack,
                                              u32* __restrict__ xout, int mode) {
    int wid = threadIdx.x >> 6;
    u32 lane = threadIdx.x & 63;
    int slice = blockIdx.x / 12500;
    int row = (blockIdx.x % 12500) * 4 + wid;
    row = __builtin_amdgcn_readfirstlane(row);
    int beg = row_ptr[row];
    int end = row_ptr[row + 1];
    int es = (int)(lane >> 2);
    u32 c4 = lane & 3;

    const u32* xs = x + (size_t)slice * SLAB;
    float ax[4] = {0.f, 0.f, 0.f, 0.f};
    float ay[4] = {0.f, 0.f, 0.f, 0.f};

    for (int e = beg; e < end; e += 16) {
        u32 rec = epack[e + es];
        uint4 gv = *(const uint4*)(xs + (rec & 0xffffu) * 16 + c4 * 4);
        float w = unpack_f16hi(rec);
        ax[0] += w * bflo(gv.x); ay[0] += w * bfhi(gv.x);
        ax[1] += w * bflo(gv.y); ay[1] += w * bfhi(gv.y);
        ax[2] += w * bflo(gv.z); ay[2] += w * bfhi(gv.z);
        ax[3] += w * bflo(gv.w); ay[3] += w * bfhi(gv.w);
    }

    #pragma unroll
    for (int m = 4; m <= 32; m <<= 1) {
        #pragma unroll
        for (int j = 0; j < 4; ++j) {
            ax[j] += __shfl_xor(ax[j], m, 64);
            ay[j] += __shfl_xor(ay[j], m, 64);
        }
    }

    if (lane < 4) {  // lane == chunk c4
        u32 off = (u32)row * 16 + lane * 4;
        if (mode) {
            uint4 pv = *(const uint4*)(xprev + (size_t)slice * SLAB + off);
            ax[0] = 2.f * ax[0] - bflo(pv.x); ay[0] = 2.f * ay[0] - bfhi(pv.x);
            ax[1] = 2.f * ax[1] - bflo(pv.y); ay[1] = 2.f * ay[1] - bfhi(pv.y);
            ax[2] = 2.f * ax[2] - bflo(pv.z); ay[2] = 2.f * ay[2] - bfhi(pv.z);
            ax[3] = 2.f * ax[3] - bflo(pv.w); ay[3] = 2.f * ay[3] - bfhi(pv.w);
        }
        uint4 o;
        o.x = pack_bf2(ax[0], ay[0]);
        o.y = pack_bf2(ax[1], ay[1]);
        o.z = pack_bf2(ax[2], ay[2]);
        o.w = pack_bf2(ax[3], ay[3]);
        *(uint4*)(xout + (size_t)slice * SLAB + off) = o;
    }
}

// MFMA epilogue: C[100000 x 64] = X[100000 x 256] @ W'[256 x 64] + bias.
// A-frag from slab layout: u16 idx i16 = b*64+f0 -> slab slice i16>>5, within i16&31.
__global__ __launch_bounds__(256) void final_k(const u16* __restrict__ x_all,
                                               const u16* __restrict__ wimg,
                                               const float* __restrict__ bias,
                                               float* __restrict__ out) {
    __shared__ u16 Wt[64 * 264];
    {
        const u32* src = (const u32*)wimg;
        u32* dst = (u32*)Wt;
        #pragma unroll 4
        for (int i = threadIdx.x; i < 64 * 264 / 2; i += 256) dst[i] = src[i];
    }
    __syncthreads();

    int lane = threadIdx.x & 63;
    int wid = threadIdx.x >> 6;
    int pair = blockIdx.x * 4 + wid;
    int t0 = pair * 2;
    if (t0 >= NTILES) return;

    int m = lane & 15;
    int q8 = (lane >> 4) * 8;

    int r0 = t0 * 16 + m;
    int r1 = r0 + 16;
    int v0 = r0 >> 1, b0 = r0 & 1;
    int v1 = r1 >> 1, b1 = r1 & 1;

    f32x4 accA[4] = {{0,0,0,0},{0,0,0,0},{0,0,0,0},{0,0,0,0}};
    f32x4 accB[4] = {{0,0,0,0},{0,0,0,0},{0,0,0,0},{0,0,0,0}};

    #pragma unroll
    for (int kb = 0; kb < 8; ++kb) {
        int cb = kb * 32 + q8;
        int arr = cb >> 6;
        int f0 = cb & 63;
        int i16a = b0 * 64 + f0;
        int i16b = b1 * 64 + f0;
        const u16* pa = x_all + ((size_t)arr * 4 + (i16a >> 5)) * (SLAB * 2)
                              + (size_t)v0 * 32 + (i16a & 31);
        const u16* pb = x_all + ((size_t)arr * 4 + (i16b >> 5)) * (SLAB * 2)
                              + (size_t)v1 * 32 + (i16b & 31);
        bf16x8 a0 = *(const bf16x8*)pa;
        bf16x8 a1 = *(const bf16x8*)pb;
        #pragma unroll
        for (int j = 0; j < 4; ++j) {
            bf16x8 bj = *(const bf16x8*)&Wt[(j * 16 + m) * 264 + kb * 32 + q8];
            accA[j] = __builtin_amdgcn_mfma_f32_16x16x32_bf16(a0, bj, accA[j], 0, 0, 0);
            accB[j] = __builtin_amdgcn_mfma_f32_16x16x32_bf16(a1, bj, accB[j], 0, 0, 0);
        }
    }

    float bv[4];
    #pragma unroll
    for (int j = 0; j < 4; ++j) bv[j] = bias[j * 16 + m];

    #pragma unroll
    for (int half = 0; half < 2; ++half) {
        int rbase = (t0 + half) * 16 + (lane >> 4) * 4;
        f32x4* acc = half ? accB : accA;
        #pragma unroll
        for (int reg = 0; reg < 4; ++reg) {
            int rr = rbase + reg;
            float* op = out + (size_t)(rr & 1) * (NV * 64) + (size_t)(rr >> 1) * 64;
            #pragma unroll
            for (int j = 0; j < 4; ++j) op[j * 16 + m] = acc[j][reg] + bv[j];
        }
    }
}

extern "C" void kernel_launch(void* const* d_in, const int* in_sizes, int n_in,
                              void* d_out, int out_size, void* d_ws, size_t ws_size,
                              hipStream_t stream) {
    const float* inputs = (const float*)d_in[0];
    const float* weight = (const float*)d_in[1];
    const float* bias   = (const float*)d_in[2];
    const float* lapv   = (const float*)d_in[3];
    const int*   lrows  = (const int*)d_in[4];
    const int*   lcols  = (const int*)d_in[5];
    float* out = (float*)d_out;

    char* ws = (char*)d_ws;
    size_t o = 0;
    auto alloc = [&](size_t bytes) -> void* {
        void* p = ws + o;
        o += (bytes + 255) & ~(size_t)255;
        return p;
    };
    u16* x_all = (u16*)alloc((size_t)4 * 4 * SLAB * 4);   // 4 arrs x 4 slabs x 3.2MB
    u32* epack = (u32*)alloc((size_t)EPMAX * 4);
    int* row_ptr = (int*)alloc((size_t)(NV + 1) * 4);
    int* row_fill = (int*)alloc((size_t)(NV + 1) * 4);
    int* cnt = (int*)alloc((size_t)NV * 4);
    int* bsum = (int*)alloc((size_t)SCAN_NBLK * 4);
    u16* wimg = (u16*)alloc((size_t)64 * 264 * 2);
    (void)ws_size; (void)in_sizes; (void)n_in; (void)out_size;

    u32* x0 = (u32*)x_all + (size_t)0 * 4 * SLAB;
    u32* x1 = (u32*)x_all + (size_t)1 * 4 * SLAB;
    u32* x2 = (u32*)x_all + (size_t)2 * 4 * SLAB;
    u32* x3 = (u32*)x_all + (size_t)3 * 4 * SLAB;

    hipMemsetAsync(cnt, 0, (size_t)NV * 4, stream);
    hipMemsetAsync(epack, 0, (size_t)EPMAX * 4, stream);
    hist_k<<<(NE + 255) / 256, 256, 0, stream>>>(lrows, cnt);
    scan1_k<<<SCAN_NBLK, 256, 0, stream>>>(cnt, bsum);
    scan2_k<<<1, 256, 0, stream>>>(bsum);
    scan3_k<<<SCAN_NBLK, 256, 0, stream>>>(cnt, bsum, row_ptr, row_fill);
    scatter_k<<<(NE + 255) / 256, 256, 0, stream>>>(lrows, lcols, lapv, row_fill, epack);
    build_x0_k<<<(NV * 64 + 255) / 256, 256, 0, stream>>>(inputs, x0);
    prep_w_k<<<64, 256, 0, stream>>>(weight, wimg);

    spmm_k<<<50000, 256, 0, stream>>>(x0, nullptr, row_ptr, epack, x1, 0);
    spmm_k<<<50000, 256, 0, stream>>>(x1, x0, row_ptr, epack, x2, 1);
    spmm_k<<<50000, 256, 0, stream>>>(x2, x1, row_ptr, epack, x3, 1);

    final_k<<<(NTILES / 2 + 3) / 4, 256, 0, stream>>>(x_all, wimg, bias, out);
}